// Round 8
// baseline (666.720 us; speedup 1.0000x reference)
//
#include <hip/hip_runtime.h>

// RGCN 2-layer forward for MI355X (gfx950). N=50000, D=128, R=16, E=1600000.
//
// Round-16: fully fused gather+gemm, barrier-free. R15 profile: gather_mean
// is the top cost (94us x2, FETCH 175MB vs ~25MB ideal - its own 200MB msg
// write stream thrashes the LLC), and gemm re-reads those 200MB. Fusion
// removes msg entirely: each wave f32-accumulates its 16 rows' segment
// means IN REGISTERS (no LDS -> no R7 write conflicts), converts to bf16
// A-fragments, and MFMAs with B-fragments loaded straight from L2-resident
// Wt (544KB hot; 1KB/wave coalesced) - so there are NO barriers at all
// (R7's serialization is structurally impossible) and waves overlap each
// other's gather latency via TLP. Numerics identical to the split path.
// Sort/conv identical to R15.
//
// ws: h_bf | x_bf | Wt1 | Wt2 | seg_off | cnt_inv | sorted_src | ctl |
//     coarse_buf (sort phase only)

#define ND 128
#define NR 16
#define KPB 4096              // keys per coarse bucket

typedef __attribute__((ext_vector_type(8))) short bf16x8;
typedef __attribute__((ext_vector_type(4))) float f32x4;

__device__ __forceinline__ unsigned short f2b(float f) {
    unsigned u = __float_as_uint(f);
    u += 0x7FFFu + ((u >> 16) & 1u);          // round-to-nearest-even
    return (unsigned short)(u >> 16);
}

// ------------------------------------------------------------ coarse hist ---
__global__ __launch_bounds__(256) void coarse_hist(
    const int* __restrict__ dst, const int* __restrict__ rel,
    int* __restrict__ coarse_cnt, int E, int N, int NBK)
{
    __shared__ int h[1024];
    const int t = threadIdx.x;
    for (int i = t; i < NBK; i += 256) h[i] = 0;
    __syncthreads();
#pragma unroll
    for (int q = 0; q < 16; ++q) {
        int e = blockIdx.x * KPB + q * 256 + t;
        if (e < E) {
            int key = rel[e] * N + dst[e];
            atomicAdd(&h[key >> 12], 1);
        }
    }
    __syncthreads();
    for (int i = t; i < NBK; i += 256)
        if (h[i]) atomicAdd(&coarse_cnt[i], h[i]);
}

// ------------------------------------------------------------ coarse scan ---
__global__ __launch_bounds__(1024) void coarse_scan(
    const int* __restrict__ coarse_cnt, int* __restrict__ cscan,
    int* __restrict__ coarse_cursor, int NBK, int E)
{
    __shared__ int sdata[1024];
    const int t = threadIdx.x;
    int v = (t < NBK) ? coarse_cnt[t] : 0;
    sdata[t] = v;
    __syncthreads();
    for (int off = 1; off < 1024; off <<= 1) {
        int tmp = (t >= off) ? sdata[t - off] : 0;
        __syncthreads();
        sdata[t] += tmp;
        __syncthreads();
    }
    if (t < NBK) {
        int excl = sdata[t] - v;
        cscan[t] = excl;
        coarse_cursor[t] = excl;
    }
    if (t == 0) cscan[NBK] = E;
}

// --------------------------------------------------------- fill A (bucket) ---
__global__ __launch_bounds__(256) void fillA(
    const int* __restrict__ src, const int* __restrict__ dst,
    const int* __restrict__ rel, int* __restrict__ coarse_cursor,
    uint2* __restrict__ coarse_buf, int E, int N, int NBK)
{
    __shared__ uint2 pairs[KPB];
    __shared__ int h[1024];
    const int t = threadIdx.x;
    for (int i = t; i < NBK; i += 256) h[i] = 0;
    __syncthreads();
#pragma unroll
    for (int q = 0; q < 16; ++q) {
        int e = blockIdx.x * KPB + q * 256 + t;
        unsigned key = 0xFFFFFFFFu, sv = 0;
        if (e < E) {
            key = (unsigned)(rel[e] * N + dst[e]);
            sv = (unsigned)src[e];
            atomicAdd(&h[key >> 12], 1);
        }
        pairs[q * 256 + t] = make_uint2(sv, key);
    }
    __syncthreads();
    for (int i = t; i < NBK; i += 256) {
        int c = h[i];
        h[i] = c ? atomicAdd(&coarse_cursor[i], c) : 0;
    }
    __syncthreads();
#pragma unroll
    for (int q = 0; q < 16; ++q) {
        uint2 p = pairs[q * 256 + t];
        if (p.y != 0xFFFFFFFFu) {
            int pos = atomicAdd(&h[p.y >> 12], 1);
            coarse_buf[pos] = p;
        }
    }
}

// ---------------------------------------------- fill B (local sort+outputs) ---
__global__ __launch_bounds__(256) void fillB(
    const uint2* __restrict__ coarse_buf, const int* __restrict__ cscan,
    int* __restrict__ seg_off, float* __restrict__ cnt_inv,
    int* __restrict__ sorted_src, int M, int E, int NBK)
{
    __shared__ int cnt[KPB];
    __shared__ int w[256];
    const int t = threadIdx.x;
    const int b = blockIdx.x;
    const int kbase = b << 12;
    const int nkeys = min(KPB, M - kbase);
    const int r0 = cscan[b], r1 = cscan[b + 1];

    for (int i = t; i < KPB; i += 256) cnt[i] = 0;
    __syncthreads();
    for (int e = r0 + t; e < r1; e += 256)
        atomicAdd(&cnt[coarse_buf[e].y - kbase], 1);
    __syncthreads();
    for (int i = t; i < nkeys; i += 256)
        cnt_inv[kbase + i] = 1.0f / fmaxf((float)cnt[i], 1.0f);
    int s = 0;
#pragma unroll
    for (int j = 0; j < 16; ++j) s += cnt[t * 16 + j];
    w[t] = s;
    __syncthreads();
    for (int off = 1; off < 256; off <<= 1) {
        int tmp = (t >= off) ? w[t - off] : 0;
        __syncthreads();
        w[t] += tmp;
        __syncthreads();
    }
    int run = r0 + w[t] - s;
#pragma unroll
    for (int j = 0; j < 16; ++j) {
        int i = t * 16 + j;
        int c = cnt[i];
        cnt[i] = run;
        if (i < nkeys) seg_off[kbase + i] = run;
        run += c;
    }
    if (b == NBK - 1 && t == 0) seg_off[M] = E;
    __syncthreads();
    for (int e = r0 + t; e < r1; e += 256) {
        uint2 p = coarse_buf[e];
        int pos = atomicAdd(&cnt[p.y - kbase], 1);
        sorted_src[pos] = (int)p.x;
    }
}

// --------------------------------------------------------------- convert ---
__global__ __launch_bounds__(256) void conv_x_kernel(
    const float* __restrict__ x, unsigned short* __restrict__ xb, int n4)
{
    int i = blockIdx.x * 256 + threadIdx.x;
    if (i >= n4) return;
    float4 v = ((const float4*)x)[i];
    uint2 o;
    o.x = (unsigned)f2b(v.x) | ((unsigned)f2b(v.y) << 16);
    o.y = (unsigned)f2b(v.z) | ((unsigned)f2b(v.w) << 16);
    ((uint2*)xb)[i] = o;
}

// Weights in MFMA-fragment order: Wt[mat][(kt*8+ct)*64+lane][8 shorts],
// frag(lane) = { n = ct*16 + (lane&15), k = kt*32 + (lane>>4)*8 .. +8 }.
__global__ __launch_bounds__(256) void conv_w_kernel(
    const float* __restrict__ W, const float* __restrict__ root,
    unsigned short* __restrict__ Wt)
{
    int t = blockIdx.x * 256 + threadIdx.x;
    if (t >= 17 * 2048) return;
    int mat = t >> 11;
    int f = t & 2047;
    int lane = f & 63;
    int ctkt = f >> 6;
    int kt = ctkt >> 3;
    int ct = ctkt & 7;
    int n = ct * 16 + (lane & 15);
    int k = kt * 32 + (lane >> 4) * 8;
    const float* s = (mat < 16) ? (W + (size_t)mat * 16384) : root;
    uint4 o;
    o.x = (unsigned)f2b(s[(size_t)(k + 0) * ND + n]) | ((unsigned)f2b(s[(size_t)(k + 1) * ND + n]) << 16);
    o.y = (unsigned)f2b(s[(size_t)(k + 2) * ND + n]) | ((unsigned)f2b(s[(size_t)(k + 3) * ND + n]) << 16);
    o.z = (unsigned)f2b(s[(size_t)(k + 4) * ND + n]) | ((unsigned)f2b(s[(size_t)(k + 5) * ND + n]) << 16);
    o.w = (unsigned)f2b(s[(size_t)(k + 6) * ND + n]) | ((unsigned)f2b(s[(size_t)(k + 7) * ND + n]) << 16);
    *(uint4*)(Wt + (size_t)t * 8) = o;
}

// --------------------------------------------------------- fused RGCN layer ---
// 256 threads = 4 waves; block covers 64 rows (wave wv: rows blk*64+wv*16).
// NO LDS, NO barriers. Per relation: each lane f32-accumulates the segment
// mean of its (row, quad) A-chunk in registers (CSR walk), packs to bf16
// fragments, then 32 MFMA with B-fragments loaded directly from L2-resident
// Wt (coalesced 1KB/wave per fragment). Waves are fully independent; TLP
// hides the gather chains. acc += root(A@Wroot) + sum_r mean_r @ W_r.
__global__ __launch_bounds__(256, 4) void rgcn_fused(
    const unsigned short* __restrict__ A,     // N x 128 bf16 (x_bf or h_bf)
    const unsigned short* __restrict__ Wt,    // [17][2048][8] swizzled bf16
    const int* __restrict__ seg_off,          // [R*N + 1]
    const int* __restrict__ sorted_src,       // [E]
    const float* __restrict__ cnt_inv,        // [R*N]
    const float* __restrict__ bias,
    unsigned short* __restrict__ out_bf,      // layer-1 dest or null
    float* __restrict__ out_f32,              // layer-2 dest or null
    int N)
{
    const int tid = threadIdx.x;
    const int lane = tid & 63;
    const int wv = tid >> 6;
    const int quad = lane >> 4;
    const int l16 = lane & 15;
    const int m0 = blockIdx.x * 64 + wv * 16;
    const int arow = m0 + l16;
    const bool rowok = (arow < N);
    const bf16x8 zfrag = {0, 0, 0, 0, 0, 0, 0, 0};

    f32x4 acc[8];
#pragma unroll
    for (int ct = 0; ct < 8; ++ct) { f32x4 z = {0.f, 0.f, 0.f, 0.f}; acc[ct] = z; }

    // ---- root term: A-fragments straight from the feature table ----
    {
        bf16x8 a[4];
#pragma unroll
        for (int kt = 0; kt < 4; ++kt)
            a[kt] = rowok ? *(const bf16x8*)(A + (size_t)arow * ND + kt * 32 + quad * 8) : zfrag;
        const unsigned short* B = Wt + (size_t)16 * 2048 * 8;
#pragma unroll
        for (int kt = 0; kt < 4; ++kt)
#pragma unroll
            for (int ct = 0; ct < 8; ++ct) {
                bf16x8 b = *(const bf16x8*)(B + (size_t)((kt * 8 + ct) * 64 + lane) * 8);
                acc[ct] = __builtin_amdgcn_mfma_f32_16x16x32_bf16(a[kt], b, acc[ct], 0, 0, 0);
            }
    }

    // ---- relation terms: register-held segment-mean gather + MFMA ----
    for (int rel = 0; rel < NR; ++rel) {
        int s = rel * N + (rowok ? arow : 0);
        int b0 = 0, e1 = 0;
        float inv = 0.f;
        if (rowok) { b0 = seg_off[s]; e1 = seg_off[s + 1]; inv = cnt_inv[s]; }

        float ga[4][8];
#pragma unroll
        for (int kt = 0; kt < 4; ++kt)
#pragma unroll
            for (int j = 0; j < 8; ++j) ga[kt][j] = 0.f;

        for (int e = b0; e < e1; ++e) {
            int src = sorted_src[e];
            const unsigned short* rp = A + (size_t)src * ND + quad * 8;
#pragma unroll
            for (int kt = 0; kt < 4; ++kt) {
                uint4 u = *(const uint4*)(rp + kt * 32);
                ga[kt][0] += __uint_as_float(u.x << 16);
                ga[kt][1] += __uint_as_float(u.x & 0xFFFF0000u);
                ga[kt][2] += __uint_as_float(u.y << 16);
                ga[kt][3] += __uint_as_float(u.y & 0xFFFF0000u);
                ga[kt][4] += __uint_as_float(u.z << 16);
                ga[kt][5] += __uint_as_float(u.z & 0xFFFF0000u);
                ga[kt][6] += __uint_as_float(u.w << 16);
                ga[kt][7] += __uint_as_float(u.w & 0xFFFF0000u);
            }
        }

        bf16x8 a[4];
#pragma unroll
        for (int kt = 0; kt < 4; ++kt) {
            bf16x8 t;
#pragma unroll
            for (int j = 0; j < 8; ++j) t[j] = (short)f2b(ga[kt][j] * inv);
            a[kt] = t;
        }

        const unsigned short* B = Wt + (size_t)rel * 2048 * 8;
#pragma unroll
        for (int kt = 0; kt < 4; ++kt)
#pragma unroll
            for (int ct = 0; ct < 8; ++ct) {
                bf16x8 b = *(const bf16x8*)(B + (size_t)((kt * 8 + ct) * 64 + lane) * 8);
                acc[ct] = __builtin_amdgcn_mfma_f32_16x16x32_bf16(a[kt], b, acc[ct], 0, 0, 0);
            }
    }

    // ---- epilogue: bias + ReLU ----
#pragma unroll
    for (int ct = 0; ct < 8; ++ct) {
        float bb = bias[ct * 16 + l16];
#pragma unroll
        for (int rg = 0; rg < 4; ++rg) {
            int r = m0 + quad * 4 + rg;
            if (r < N) {
                float v = fmaxf(acc[ct][rg] + bb, 0.f);
                if (out_bf) out_bf[(size_t)r * ND + ct * 16 + l16] = f2b(v);
                else        __builtin_nontemporal_store(v, &out_f32[(size_t)r * ND + ct * 16 + l16]);
            }
        }
    }
}

// ----------------------------------------------------------------- launch ---
extern "C" void kernel_launch(void* const* d_in, const int* in_sizes, int n_in,
                              void* d_out, int out_size, void* d_ws, size_t ws_size,
                              hipStream_t stream) {
    const float* x     = (const float*)d_in[0];
    const int*   eidx  = (const int*)d_in[1];
    const int*   etype = (const int*)d_in[2];
    const float* W1    = (const float*)d_in[3];
    const float* root1 = (const float*)d_in[4];
    const float* b1    = (const float*)d_in[5];
    const float* W2    = (const float*)d_in[6];
    const float* root2 = (const float*)d_in[7];
    const float* b2    = (const float*)d_in[8];
    float* out = (float*)d_out;

    const int N = in_sizes[0] / ND;
    const int E = in_sizes[2];
    const int M = NR * N;
    const int NBK = (M + KPB - 1) / KPB;

    const int* src = eidx;
    const int* dst = eidx + E;

    // --- workspace carve-up ---
    char* p = (char*)d_ws;
    auto carve = [&](size_t bytes) { char* q = p; p += (bytes + 255) & ~(size_t)255; return q; };
    unsigned short* h_bf    = (unsigned short*)carve((size_t)N * ND * 2);
    unsigned short* x_bf    = (unsigned short*)carve((size_t)N * ND * 2);
    unsigned short* Wt1     = (unsigned short*)carve((size_t)17 * 2048 * 8 * 2);
    unsigned short* Wt2     = (unsigned short*)carve((size_t)17 * 2048 * 8 * 2);
    int*   seg_off          = (int*)  carve((size_t)(M + 1) * 4);
    float* cnt_inv          = (float*)carve((size_t)M * 4);
    int*   sorted_src       = (int*)  carve((size_t)E * 4);
    int*   coarse_cnt       = (int*)  carve(1024 * 4);
    int*   cscan            = (int*)  carve(1025 * 4);
    int*   coarse_cursor    = (int*)  carve(1024 * 4);
    uint2* coarse_buf       = (uint2*)p;                 // sort phase only

    const int eb4 = (E + KPB - 1) / KPB;
    const int fused_blocks = (N + 63) / 64;

    // --- two-level counting sort by (rel, dst) ---
    hipMemsetAsync(coarse_cnt, 0, 1024 * 4, stream);
    coarse_hist<<<eb4, 256, 0, stream>>>(dst, etype, coarse_cnt, E, N, NBK);
    coarse_scan<<<1, 1024, 0, stream>>>(coarse_cnt, cscan, coarse_cursor, NBK, E);
    fillA<<<eb4, 256, 0, stream>>>(src, dst, etype, coarse_cursor, coarse_buf, E, N, NBK);
    fillB<<<NBK, 256, 0, stream>>>(coarse_buf, cscan, seg_off, cnt_inv, sorted_src, M, E, NBK);

    // --- bf16 conversions ---
    conv_x_kernel<<<((N * ND / 4) + 255) / 256, 256, 0, stream>>>(x, x_bf, N * ND / 4);
    conv_w_kernel<<<(17 * 2048 + 255) / 256, 256, 0, stream>>>(W1, root1, Wt1);
    conv_w_kernel<<<(17 * 2048 + 255) / 256, 256, 0, stream>>>(W2, root2, Wt2);

    // --- two fused layers ---
    rgcn_fused<<<fused_blocks, 256, 0, stream>>>(
        x_bf, Wt1, seg_off, sorted_src, cnt_inv, b1, h_bf, (float*)nullptr, N);
    rgcn_fused<<<fused_blocks, 256, 0, stream>>>(
        h_bf, Wt2, seg_off, sorted_src, cnt_inv, b2, (unsigned short*)nullptr, out, N);
}